// Round 11
// baseline (233.678 us; speedup 1.0000x reference)
//
#include <hip/hip_runtime.h>

#define F_IN 64
#define NH 4
#define HC 128
#define NEG_SLOPE 0.2f
#define LN_EPS 1e-5f
#define NC_CHUNK 128          // number of edge chunks
#define BUCKET 128            // dst nodes per bucket

typedef __bf16 bf16_8 __attribute__((ext_vector_type(8)));
typedef float  f32_4  __attribute__((ext_vector_type(4)));

// ---------------------------------------------------------------------------
// K0: detect whether edge_index arrived as int64 (little-endian) or int32.
// ---------------------------------------------------------------------------
__global__ void k0_detect(const int* __restrict__ ei, int E, int* __restrict__ flag) {
    __shared__ int any_nz;
    if (threadIdx.x == 0) any_nz = 0;
    __syncthreads();
    long long stride = (2LL * E) / 257;
    long long pos = (long long)(threadIdx.x + 1) * stride;
    int w = ei[pos | 1];
    if (w != 0) atomicOr(&any_nz, 1);
    __syncthreads();
    if (threadIdx.x == 0) flag[0] = (any_nz == 0) ? 1 : 0;   // 1 => int64
}

__device__ inline unsigned bfpack(float a, float b) {
    unsigned ua = __float_as_uint(a), ub = __float_as_uint(b);
    ua = (ua + 0x7fffu + ((ua >> 16) & 1u)) >> 16;           // RNE to bf16
    ub = (ub + 0x7fffu + ((ub >> 16) & 1u)) >> 16;
    return ua | (ub << 16);
}

__device__ inline float wave_bcast_sum(float v) {
#pragma unroll
    for (int off = 32; off > 0; off >>= 1) v += __shfl_down(v, off, 64);
    return __shfl(v, 0, 64);
}

// ---------------------------------------------------------------------------
// KW_prep: one-time transpose+convert of Wcat = [W | res_w] into bf16
// wt[ch*64 + k], ch in [0,256), k in [0,64). 32 KB total -> L2-resident.
// ---------------------------------------------------------------------------
__global__ __launch_bounds__(256) void kW_prep(
    const float* __restrict__ W, const float* __restrict__ res_w,
    __bf16* __restrict__ wt)
{
    int idx = blockIdx.x * 256 + threadIdx.x;    // 0..16383
    int ch = idx >> 6, k = idx & 63;
    const float* src = (ch < HC) ? W : res_w;
    wt[ch * 64 + k] = (__bf16)src[k * HC + (ch & (HC - 1))];
}

// ---------------------------------------------------------------------------
// KA (MFMA, no LDS): h_bf16 = x@W, r_bf16 = x@res_w, + fused attention logits.
// A-frags straight from pre-transposed wt (L1/L2-resident 32 KB);
// B-frags from x. Layout correctness-proven in R10:
// A[m=ch via lane&15][k=quad*8+j], B[k][n=node via lane&15],
// D[row=quad*4+reg -> ch][col=lane&15 -> node].
// ---------------------------------------------------------------------------
__global__ __launch_bounds__(256) void kA_mfma(
    const float* __restrict__ x, const __bf16* __restrict__ wt,
    const float* __restrict__ att_src, const float* __restrict__ att_dst,
    unsigned* __restrict__ h_bf, unsigned* __restrict__ r_bf,
    float* __restrict__ a_s, float* __restrict__ a_d, int n)
{
    int tid = threadIdx.x;
    int wv_ = tid >> 6, lane = tid & 63;
    int col = lane & 15, quad = lane >> 4;
    int node = blockIdx.x * 64 + wv_ * 16 + col;
    int nrow = (node < n) ? node : (n - 1);

    // B-frags: x[nrow][quad*8 + (0..7)] for k-halves 0 (k+0) and 1 (k+32)
    bf16_8 bx0, bx1;
    {
        const float* xp = &x[nrow * F_IN + quad * 8];
        float4 p0 = *(const float4*)(xp);
        float4 p1 = *(const float4*)(xp + 4);
        float4 p2 = *(const float4*)(xp + 32);
        float4 p3 = *(const float4*)(xp + 36);
        bx0[0] = (__bf16)p0.x; bx0[1] = (__bf16)p0.y; bx0[2] = (__bf16)p0.z; bx0[3] = (__bf16)p0.w;
        bx0[4] = (__bf16)p1.x; bx0[5] = (__bf16)p1.y; bx0[6] = (__bf16)p1.z; bx0[7] = (__bf16)p1.w;
        bx1[0] = (__bf16)p2.x; bx1[1] = (__bf16)p2.y; bx1[2] = (__bf16)p2.z; bx1[3] = (__bf16)p2.w;
        bx1[4] = (__bf16)p3.x; bx1[5] = (__bf16)p3.y; bx1[6] = (__bf16)p3.z; bx1[7] = (__bf16)p3.w;
    }

    float vs[4] = {0.f, 0.f, 0.f, 0.f};
    float vd[4] = {0.f, 0.f, 0.f, 0.f};

#pragma unroll
    for (int mt = 0; mt < 16; ++mt) {
        const __bf16* ap = &wt[(mt * 16 + col) * 64 + quad * 8];
        bf16_8 a0 = *(const bf16_8*)ap;
        bf16_8 a1 = *(const bf16_8*)(ap + 32);
        f32_4 acc = {0.f, 0.f, 0.f, 0.f};
        acc = __builtin_amdgcn_mfma_f32_16x16x32_bf16(a0, bx0, acc, 0, 0, 0);
        acc = __builtin_amdgcn_mfma_f32_16x16x32_bf16(a1, bx1, acc, 0, 0, 0);
        int ch0 = mt * 16 + quad * 4;
        if (mt < 8) {
            float4 as4 = *(const float4*)&att_src[ch0];
            float4 ad4 = *(const float4*)&att_dst[ch0];
            int head = mt >> 1;
            vs[head] += acc[0] * as4.x + acc[1] * as4.y + acc[2] * as4.z + acc[3] * as4.w;
            vd[head] += acc[0] * ad4.x + acc[1] * ad4.y + acc[2] * ad4.z + acc[3] * ad4.w;
            if (node < n) {
                uint2 pk = make_uint2(bfpack(acc[0], acc[1]), bfpack(acc[2], acc[3]));
                *(uint2*)&h_bf[node * 64 + (ch0 >> 1)] = pk;
            }
        } else {
            if (node < n) {
                uint2 pk = make_uint2(bfpack(acc[0], acc[1]), bfpack(acc[2], acc[3]));
                *(uint2*)&r_bf[node * 64 + ((ch0 - 128) >> 1)] = pk;
            }
        }
    }

#pragma unroll
    for (int hh = 0; hh < NH; ++hh) {
        vs[hh] += __shfl_down(vs[hh], 32, 64);
        vs[hh] += __shfl_down(vs[hh], 16, 64);
        vd[hh] += __shfl_down(vd[hh], 32, 64);
        vd[hh] += __shfl_down(vd[hh], 16, 64);
    }
    if (quad == 0 && node < n) {
        *(float4*)&a_s[node * NH] = make_float4(vs[0], vs[1], vs[2], vs[3]);
        *(float4*)&a_d[node * NH] = make_float4(vd[0], vd[1], vd[2], vd[3]);
    }
}

// ---------------------------------------------------------------------------
// KC_count: chunk c histograms ITS OWN edges by dst bucket (LDS); folds
// scan-phase-1 via atomicAdd into bsums.
// ---------------------------------------------------------------------------
__global__ __launch_bounds__(256) void kc_count(
    const int* __restrict__ ei, int E, const int* __restrict__ flag,
    int* __restrict__ counts, int* __restrict__ bsums, int NB, int chunk)
{
    __shared__ int cnt[512];
    int c = blockIdx.x;
    for (int i = threadIdx.x; i < NB; i += 256) cnt[i] = 0;
    __syncthreads();
    int base = c * chunk, end = min(E, base + chunk);
    int is64 = flag[0];
    for (int idx = base + threadIdx.x; idx < end; idx += 256) {
        int d = is64 ? ei[2 * (E + idx)] : ei[E + idx];
        atomicAdd(&cnt[d >> 7], 1);
    }
    __syncthreads();
    for (int b = threadIdx.x; b < NB; b += 256) {
        int v = cnt[b];
        counts[b * NC_CHUNK + c] = v;
        if (v) atomicAdd(&bsums[(b * NC_CHUNK + c) >> 8], v);
    }
}

__global__ __launch_bounds__(256) void k_scan_p2(int* __restrict__ bsums, int nblk)
{
    __shared__ int sh[256];
    int t = threadIdx.x;
    int v = (t < nblk) ? bsums[t] : 0;
    sh[t] = v;
    __syncthreads();
#pragma unroll
    for (int off = 1; off < 256; off <<= 1) {
        int u = (t >= off) ? sh[t - off] : 0;
        __syncthreads();
        sh[t] += u;
        __syncthreads();
    }
    if (t < nblk) bsums[t] = sh[t] - v;
}

__global__ __launch_bounds__(256) void k_scan_p3(int* __restrict__ arr,
                                                 const int* __restrict__ bsums,
                                                 int M, int E)
{
    __shared__ int sh[256];
    int t = threadIdx.x;
    int i = blockIdx.x * 256 + t;
    int v = (i < M) ? arr[i] : 0;
    sh[t] = v;
    __syncthreads();
#pragma unroll
    for (int off = 1; off < 256; off <<= 1) {
        int u = (t >= off) ? sh[t - off] : 0;
        __syncthreads();
        sh[t] += u;
        __syncthreads();
    }
    int excl = sh[t] - v + bsums[blockIdx.x];
    if (i < M) arr[i] = excl;
    if (blockIdx.x == 0 && t == 0) arr[M] = E;
}

// ---------------------------------------------------------------------------
// KC_scatter: chunk c writes packed (dst_local<<16 | src) into its private
// per-bucket slices (LDS cursors). Requires n <= 65536.
// ---------------------------------------------------------------------------
__global__ __launch_bounds__(1024) void kc_scatter(
    const int* __restrict__ ei, int E, const int* __restrict__ flag,
    const int* __restrict__ off, int NB, int chunk, int* __restrict__ epacked)
{
    __shared__ int cur[512];
    int c = blockIdx.x;
    for (int b = threadIdx.x; b < NB; b += 1024) cur[b] = off[b * NC_CHUNK + c];
    __syncthreads();
    int base = c * chunk, end = min(E, base + chunk);
    int is64 = flag[0];
    for (int idx = base + threadIdx.x; idx < end; idx += 1024) {
        int s = is64 ? ei[2 * idx] : ei[idx];
        int d = is64 ? ei[2 * (E + idx)] : ei[E + idx];
        int p = atomicAdd(&cur[d >> 7], 1);
        epacked[p] = ((d & (BUCKET - 1)) << 16) | s;
    }
}

// ---------------------------------------------------------------------------
// KD_sort: one block per bucket -> per-dst CSR order within the bucket's
// private global range; emits node-level offsets.
// ---------------------------------------------------------------------------
__global__ __launch_bounds__(256) void kd_sort(
    const int* __restrict__ off, const int* __restrict__ epacked,
    int* __restrict__ sorted_src, int* __restrict__ offsets,
    int NB, int n, int E)
{
    __shared__ int hist[BUCKET];
    __shared__ int sc[BUCKET];
    __shared__ int cur[BUCKET];
    int b = blockIdx.x;
    int s0 = off[b * NC_CHUNK];
    int s1 = off[(b + 1) * NC_CHUNK];
    int t = threadIdx.x;
    if (t < BUCKET) hist[t] = 0;
    __syncthreads();
    for (int e = s0 + t; e < s1; e += 256)
        atomicAdd(&hist[((unsigned)epacked[e]) >> 16], 1);
    __syncthreads();
    if (t < BUCKET) sc[t] = hist[t];
    __syncthreads();
#pragma unroll
    for (int o = 1; o < BUCKET; o <<= 1) {
        int u = (t >= o && t < BUCKET) ? sc[t - o] : 0;
        __syncthreads();
        if (t < BUCKET) sc[t] += u;
        __syncthreads();
    }
    if (t < BUCKET) {
        int excl = sc[t] - hist[t];
        cur[t] = s0 + excl;
        int d = b * BUCKET + t;
        if (d < n) offsets[d] = s0 + excl;
    }
    if (b == NB - 1 && t == 0) offsets[n] = E;
    __syncthreads();
    for (int e = s0 + t; e < s1; e += 256) {
        int p = epacked[e];
        int pos = atomicAdd(&cur[((unsigned)p) >> 16], 1);
        sorted_src[pos] = p & 0xFFFF;
    }
}

// ---------------------------------------------------------------------------
// K_agg: wave-per-dst CSR gather, register accumulation, fused epilogue.
// ---------------------------------------------------------------------------
__global__ __launch_bounds__(256) void k_agg(
    const int* __restrict__ offsets, const int* __restrict__ src_sorted,
    const float* __restrict__ a_s, const float* __restrict__ a_d,
    const unsigned int* __restrict__ h_bf, const unsigned int* __restrict__ r_bf,
    const float* __restrict__ bias, const float* __restrict__ res_b,
    const float* __restrict__ ln_g, const float* __restrict__ ln_b,
    float* __restrict__ out, int n)
{
    int wv = threadIdx.x >> 6, lane = threadIdx.x & 63;
    int d = blockIdx.x * 4 + wv;
    if (d >= n) return;
    int c0 = lane * 2, head = lane >> 4;
    float ad = a_d[d * NH + head];

    // self-loop
    float e = a_s[d * NH + head] + ad;
    e = (e >= 0.f) ? e : NEG_SLOPE * e;
    float w = __expf(e);
    float denom = w;
    unsigned hv = h_bf[d * 64 + lane];
    float ax = w * __uint_as_float(hv << 16);
    float ay = w * __uint_as_float(hv & 0xffff0000u);

    int lo = offsets[d], hi = offsets[d + 1];
    int k = lo;
    for (; k + 7 < hi; k += 8) {
        int s[8]; unsigned v[8]; float ee[8];
#pragma unroll
        for (int i = 0; i < 8; ++i) s[i] = src_sorted[k + i];
#pragma unroll
        for (int i = 0; i < 8; ++i) ee[i] = a_s[s[i] * NH + head];
#pragma unroll
        for (int i = 0; i < 8; ++i) v[i] = h_bf[s[i] * 64 + lane];
#pragma unroll
        for (int i = 0; i < 8; ++i) {
            float e0 = ee[i] + ad;
            e0 = (e0 >= 0.f) ? e0 : NEG_SLOPE * e0;
            float w0 = __expf(e0);
            denom += w0;
            ax += w0 * __uint_as_float(v[i] << 16);
            ay += w0 * __uint_as_float(v[i] & 0xffff0000u);
        }
    }
    for (; k < hi; ++k) {
        int s0 = src_sorted[k];
        float e0 = a_s[s0 * NH + head] + ad;
        unsigned v0 = h_bf[s0 * 64 + lane];
        e0 = (e0 >= 0.f) ? e0 : NEG_SLOPE * e0;
        float w0 = __expf(e0);
        denom += w0;
        ax += w0 * __uint_as_float(v0 << 16);
        ay += w0 * __uint_as_float(v0 & 0xffff0000u);
    }

    float inv = 1.f / denom;
    float ox = ax * inv + bias[c0];
    float oy = ay * inv + bias[c0 + 1];
    ox = (ox > 0.f) ? ox : expm1f(ox);
    oy = (oy > 0.f) ? oy : expm1f(oy);
    unsigned rv = r_bf[d * 64 + lane];
    ox += __uint_as_float(rv << 16) + res_b[c0];
    oy += __uint_as_float(rv & 0xffff0000u) + res_b[c0 + 1];
    float mean = wave_bcast_sum(ox + oy) * (1.f / HC);
    float dx = ox - mean, dy = oy - mean;
    float var = wave_bcast_sum(dx * dx + dy * dy) * (1.f / HC);
    float rs = rsqrtf(var + LN_EPS);
    *(float2*)&out[d * HC + c0] =
        make_float2(ln_g[c0] * dx * rs + ln_b[c0],
                    ln_g[c0 + 1] * dy * rs + ln_b[c0 + 1]);
}

// ---------------------------------------------------------------------------
extern "C" void kernel_launch(void* const* d_in, const int* in_sizes, int n_in,
                              void* d_out, int out_size, void* d_ws, size_t ws_size,
                              hipStream_t stream) {
    const float* x       = (const float*)d_in[0];
    const int*   ei      = (const int*)d_in[1];
    const float* W       = (const float*)d_in[2];
    const float* att_src = (const float*)d_in[3];
    const float* att_dst = (const float*)d_in[4];
    const float* bias    = (const float*)d_in[5];
    const float* res_w   = (const float*)d_in[6];
    const float* res_b   = (const float*)d_in[7];
    const float* ln_g    = (const float*)d_in[8];
    const float* ln_b    = (const float*)d_in[9];
    float* out = (float*)d_out;

    int n = in_sizes[0] / F_IN;              // 50000 (<= 65536 for packing)
    int E = in_sizes[1] / 2;                 // 800000
    int NB = (n + BUCKET - 1) / BUCKET;      // 391 buckets (<= 512)
    int chunk = (E + NC_CHUNK - 1) / NC_CHUNK;
    int M = NB * NC_CHUNK;                   // 50048
    int nblk = (M + 255) / 256;              // 196 (<= 256)

    unsigned* h_bf     = (unsigned*)d_ws;                  // n*64 dwords
    unsigned* r_bf     = h_bf + (size_t)n * 64;            // n*64 dwords
    float*    a_s      = (float*)(r_bf + (size_t)n * 64);  // n*NH
    float*    a_d      = a_s + (size_t)n * NH;             // n*NH
    int*      off      = (int*)(a_d + (size_t)n * NH);     // M+1
    int*      bsums    = off + (M + 1);                    // 256
    int*      epacked  = bsums + 256;                      // E
    int*      ssorted  = epacked + E;                      // E
    int*      offsets  = ssorted + E;                      // n+1
    int*      flag     = offsets + (n + 1);                // 1
    __bf16*   wt       = (__bf16*)(flag + 4);              // 256*64 bf16 = 32 KB

    hipMemsetAsync(bsums, 0, 256 * sizeof(int), stream);

    k0_detect<<<1, 256, 0, stream>>>(ei, E, flag);

    kW_prep<<<64, 256, 0, stream>>>(W, res_w, wt);

    kA_mfma<<<(n + 63) / 64, 256, 0, stream>>>(
        x, wt, att_src, att_dst, h_bf, r_bf, a_s, a_d, n);

    kc_count<<<NC_CHUNK, 256, 0, stream>>>(ei, E, flag, off, bsums, NB, chunk);

    k_scan_p2<<<1, 256, 0, stream>>>(bsums, nblk);
    k_scan_p3<<<nblk, 256, 0, stream>>>(off, bsums, M, E);

    kc_scatter<<<NC_CHUNK, 1024, 0, stream>>>(ei, E, flag, off, NB, chunk, epacked);

    kd_sort<<<NB, 256, 0, stream>>>(off, epacked, ssorted, offsets, NB, n, E);

    k_agg<<<(n + 3) / 4, 256, 0, stream>>>(offsets, ssorted, a_s, a_d, h_bf, r_bf,
                                           bias, res_b, ln_g, ln_b, out, n);
}

// Round 12
// 192.769 us; speedup vs baseline: 1.2122x; 1.2122x over previous
//
#include <hip/hip_runtime.h>

#define F_IN 64
#define NH 4
#define HC 128
#define NEG_SLOPE 0.2f
#define LN_EPS 1e-5f
#define NC_CHUNK 128          // number of edge chunks
#define BUCKET 128            // dst nodes per bucket
#define KW_BLOCKS 64          // blocks doing the W transpose in k_prep

typedef __bf16 bf16_8 __attribute__((ext_vector_type(8)));
typedef float  f32_4  __attribute__((ext_vector_type(4)));

// ---------------------------------------------------------------------------
// Inline per-wave int64-vs-int32 detection: sample 64 odd dwords across the
// edge array; all-zero <=> int64 high halves (P false positive ~ (1/n)^64).
// ---------------------------------------------------------------------------
__device__ inline int detect_is64(const int* __restrict__ ei, int E) {
    int lane = threadIdx.x & 63;
    long long stride = (2LL * E) / 65;
    int w = ei[(((long long)(lane + 1)) * stride) | 1];
    return __ballot(w != 0) == 0ULL;
}

__device__ inline unsigned bfpack(float a, float b) {
    unsigned ua = __float_as_uint(a), ub = __float_as_uint(b);
    ua = (ua + 0x7fffu + ((ua >> 16) & 1u)) >> 16;           // RNE to bf16
    ub = (ub + 0x7fffu + ((ub >> 16) & 1u)) >> 16;
    return ua | (ub << 16);
}

__device__ inline float wave_bcast_sum(float v) {
#pragma unroll
    for (int off = 32; off > 0; off >>= 1) v += __shfl_down(v, off, 64);
    return __shfl(v, 0, 64);
}

// ---------------------------------------------------------------------------
// K_prep (fused dispatch 1):
//   blocks [0,64):    transpose+convert Wcat=[W|res_w] -> bf16 wt[ch*64+k]
//   blocks [64,192):  per-chunk dst-bucket histogram -> counts[c*NB+b]
// ---------------------------------------------------------------------------
__global__ __launch_bounds__(256) void k_prep(
    const float* __restrict__ W, const float* __restrict__ res_w,
    const int* __restrict__ ei, int E,
    __bf16* __restrict__ wt, int* __restrict__ counts, int NB, int chunk)
{
    if ((int)blockIdx.x < KW_BLOCKS) {
        int idx = blockIdx.x * 256 + threadIdx.x;    // 0..16383
        int ch = idx >> 6, k = idx & 63;
        const float* src = (ch < HC) ? W : res_w;
        wt[ch * 64 + k] = (__bf16)src[k * HC + (ch & (HC - 1))];
        return;
    }
    __shared__ int cnt[512];
    int c = blockIdx.x - KW_BLOCKS;
    for (int i = threadIdx.x; i < NB; i += 256) cnt[i] = 0;
    __syncthreads();
    int is64 = detect_is64(ei, E);
    int base = c * chunk, end = min(E, base + chunk);
    for (int idx = base + threadIdx.x; idx < end; idx += 256) {
        int d = is64 ? ei[2 * (E + idx)] : ei[E + idx];
        atomicAdd(&cnt[d >> 7], 1);
    }
    __syncthreads();
    for (int b = threadIdx.x; b < NB; b += 256)
        counts[c * NB + b] = cnt[b];                 // coalesced, written once
}

// ---------------------------------------------------------------------------
// K_main (fused dispatch 2):
//   blocks [0,nka):        kA MFMA dual-GEMM + fused attention logits
//   blocks [nka,nka+128):  kc_scatter — computes bucket bases + own chunk
//                          prefix redundantly from counts (no global scan),
//                          then scatters packed (dst_local<<16|src).
// ---------------------------------------------------------------------------
__global__ __launch_bounds__(256) void k_main(
    const float* __restrict__ x, const __bf16* __restrict__ wt,
    const float* __restrict__ att_src, const float* __restrict__ att_dst,
    unsigned* __restrict__ h_bf, unsigned* __restrict__ r_bf,
    float* __restrict__ a_s, float* __restrict__ a_d, int n, int nka,
    const int* __restrict__ ei, int E, const int* __restrict__ counts,
    int* __restrict__ epacked, int* __restrict__ sbase_g, int NB, int chunk)
{
    __shared__ int cur[512];
    __shared__ int ss[256];

    if ((int)blockIdx.x < nka) {
        // ---------------- kA path (proven R10/R11 layout) ----------------
        int tid = threadIdx.x;
        int wv_ = tid >> 6, lane = tid & 63;
        int col = lane & 15, quad = lane >> 4;
        int node = blockIdx.x * 64 + wv_ * 16 + col;
        int nrow = (node < n) ? node : (n - 1);

        bf16_8 bx0, bx1;
        {
            const float* xp = &x[nrow * F_IN + quad * 8];
            float4 p0 = *(const float4*)(xp);
            float4 p1 = *(const float4*)(xp + 4);
            float4 p2 = *(const float4*)(xp + 32);
            float4 p3 = *(const float4*)(xp + 36);
            bx0[0] = (__bf16)p0.x; bx0[1] = (__bf16)p0.y; bx0[2] = (__bf16)p0.z; bx0[3] = (__bf16)p0.w;
            bx0[4] = (__bf16)p1.x; bx0[5] = (__bf16)p1.y; bx0[6] = (__bf16)p1.z; bx0[7] = (__bf16)p1.w;
            bx1[0] = (__bf16)p2.x; bx1[1] = (__bf16)p2.y; bx1[2] = (__bf16)p2.z; bx1[3] = (__bf16)p2.w;
            bx1[4] = (__bf16)p3.x; bx1[5] = (__bf16)p3.y; bx1[6] = (__bf16)p3.z; bx1[7] = (__bf16)p3.w;
        }

        float vs[4] = {0.f, 0.f, 0.f, 0.f};
        float vd[4] = {0.f, 0.f, 0.f, 0.f};

#pragma unroll
        for (int mt = 0; mt < 16; ++mt) {
            const __bf16* ap = &wt[(mt * 16 + col) * 64 + quad * 8];
            bf16_8 a0 = *(const bf16_8*)ap;
            bf16_8 a1 = *(const bf16_8*)(ap + 32);
            f32_4 acc = {0.f, 0.f, 0.f, 0.f};
            acc = __builtin_amdgcn_mfma_f32_16x16x32_bf16(a0, bx0, acc, 0, 0, 0);
            acc = __builtin_amdgcn_mfma_f32_16x16x32_bf16(a1, bx1, acc, 0, 0, 0);
            int ch0 = mt * 16 + quad * 4;
            if (mt < 8) {
                float4 as4 = *(const float4*)&att_src[ch0];
                float4 ad4 = *(const float4*)&att_dst[ch0];
                int head = mt >> 1;
                vs[head] += acc[0] * as4.x + acc[1] * as4.y + acc[2] * as4.z + acc[3] * as4.w;
                vd[head] += acc[0] * ad4.x + acc[1] * ad4.y + acc[2] * ad4.z + acc[3] * ad4.w;
                if (node < n) {
                    uint2 pk = make_uint2(bfpack(acc[0], acc[1]), bfpack(acc[2], acc[3]));
                    *(uint2*)&h_bf[node * 64 + (ch0 >> 1)] = pk;
                }
            } else {
                if (node < n) {
                    uint2 pk = make_uint2(bfpack(acc[0], acc[1]), bfpack(acc[2], acc[3]));
                    *(uint2*)&r_bf[node * 64 + ((ch0 - 128) >> 1)] = pk;
                }
            }
        }

#pragma unroll
        for (int hh = 0; hh < NH; ++hh) {
            vs[hh] += __shfl_down(vs[hh], 32, 64);
            vs[hh] += __shfl_down(vs[hh], 16, 64);
            vd[hh] += __shfl_down(vd[hh], 32, 64);
            vd[hh] += __shfl_down(vd[hh], 16, 64);
        }
        if (quad == 0 && node < n) {
            *(float4*)&a_s[node * NH] = make_float4(vs[0], vs[1], vs[2], vs[3]);
            *(float4*)&a_d[node * NH] = make_float4(vd[0], vd[1], vd[2], vd[3]);
        }
        return;
    }

    // ---------------- scatter path ----------------
    int c = blockIdx.x - nka;
    int t = threadIdx.x;
    int b0 = 2 * t, b1 = 2 * t + 1;

    // full bucket sums + this chunk's prefix, from counts[c'][b] (coalesced)
    int f0 = 0, f1 = 0, p0 = 0, p1 = 0;
    for (int cc = 0; cc < NC_CHUNK; ++cc) {
        int v0 = (b0 < NB) ? counts[cc * NB + b0] : 0;
        int v1 = (b1 < NB) ? counts[cc * NB + b1] : 0;
        f0 += v0; f1 += v1;
        if (cc < c) { p0 += v0; p1 += v1; }
    }
    // exclusive scan over buckets (pair-per-thread + Hillis-Steele on sums)
    ss[t] = f0 + f1;
    __syncthreads();
#pragma unroll
    for (int off = 1; off < 256; off <<= 1) {
        int u = (t >= off) ? ss[t - off] : 0;
        __syncthreads();
        ss[t] += u;
        __syncthreads();
    }
    int ebase = ss[t] - (f0 + f1);
    int base0 = ebase;            // bucket b0 start
    int base1 = ebase + f0;       // bucket b1 start
    if (b0 < NB) cur[b0] = base0 + p0;
    if (b1 < NB) cur[b1] = base1 + p1;
    if (c == 0) {                 // publish bucket bases for kd_sort
        if (b0 <= NB) sbase_g[b0] = base0;
        if (b1 <= NB) sbase_g[b1] = base1;
    }
    __syncthreads();

    int is64 = detect_is64(ei, E);
    int base = c * chunk, end = min(E, base + chunk);
    for (int idx = base + t; idx < end; idx += 256) {
        int s = is64 ? ei[2 * idx] : ei[idx];
        int d = is64 ? ei[2 * (E + idx)] : ei[E + idx];
        int p = atomicAdd(&cur[d >> 7], 1);
        epacked[p] = ((d & (BUCKET - 1)) << 16) | s;
    }
}

// ---------------------------------------------------------------------------
// KD_sort: one block per bucket -> per-dst CSR order within the bucket's
// private global range; emits node-level offsets.
// ---------------------------------------------------------------------------
__global__ __launch_bounds__(256) void kd_sort(
    const int* __restrict__ sbase_g, const int* __restrict__ epacked,
    int* __restrict__ sorted_src, int* __restrict__ offsets,
    int NB, int n, int E)
{
    __shared__ int hist[BUCKET];
    __shared__ int sc[BUCKET];
    __shared__ int cur[BUCKET];
    int b = blockIdx.x;
    int s0 = sbase_g[b];
    int s1 = sbase_g[b + 1];
    int t = threadIdx.x;
    if (t < BUCKET) hist[t] = 0;
    __syncthreads();
    for (int e = s0 + t; e < s1; e += 256)
        atomicAdd(&hist[((unsigned)epacked[e]) >> 16], 1);
    __syncthreads();
    if (t < BUCKET) sc[t] = hist[t];
    __syncthreads();
#pragma unroll
    for (int o = 1; o < BUCKET; o <<= 1) {
        int u = (t >= o && t < BUCKET) ? sc[t - o] : 0;
        __syncthreads();
        if (t < BUCKET) sc[t] += u;
        __syncthreads();
    }
    if (t < BUCKET) {
        int excl = sc[t] - hist[t];
        cur[t] = s0 + excl;
        int d = b * BUCKET + t;
        if (d < n) offsets[d] = s0 + excl;
    }
    if (b == NB - 1 && t == 0) offsets[n] = E;
    __syncthreads();
    for (int e = s0 + t; e < s1; e += 256) {
        int p = epacked[e];
        int pos = atomicAdd(&cur[((unsigned)p) >> 16], 1);
        sorted_src[pos] = p & 0xFFFF;
    }
}

// ---------------------------------------------------------------------------
// K_agg: wave-per-dst CSR gather, register accumulation, fused epilogue.
// ---------------------------------------------------------------------------
__global__ __launch_bounds__(256) void k_agg(
    const int* __restrict__ offsets, const int* __restrict__ src_sorted,
    const float* __restrict__ a_s, const float* __restrict__ a_d,
    const unsigned int* __restrict__ h_bf, const unsigned int* __restrict__ r_bf,
    const float* __restrict__ bias, const float* __restrict__ res_b,
    const float* __restrict__ ln_g, const float* __restrict__ ln_b,
    float* __restrict__ out, int n)
{
    int wv = threadIdx.x >> 6, lane = threadIdx.x & 63;
    int d = blockIdx.x * 4 + wv;
    if (d >= n) return;
    int c0 = lane * 2, head = lane >> 4;
    float ad = a_d[d * NH + head];

    // hoisted epilogue operands (independent of the edge loop)
    unsigned rv = r_bf[d * 64 + lane];
    float bi0 = bias[c0], bi1 = bias[c0 + 1];
    float rb0 = res_b[c0], rb1 = res_b[c0 + 1];
    float g0 = ln_g[c0], g1 = ln_g[c0 + 1];
    float lb0 = ln_b[c0], lb1 = ln_b[c0 + 1];

    // self-loop
    float e = a_s[d * NH + head] + ad;
    e = (e >= 0.f) ? e : NEG_SLOPE * e;
    float w = __expf(e);
    float denom = w;
    unsigned hv = h_bf[d * 64 + lane];
    float ax = w * __uint_as_float(hv << 16);
    float ay = w * __uint_as_float(hv & 0xffff0000u);

    int lo = offsets[d], hi = offsets[d + 1];
    int k = lo;
    for (; k + 7 < hi; k += 8) {
        int s[8]; unsigned v[8]; float ee[8];
#pragma unroll
        for (int i = 0; i < 8; ++i) s[i] = src_sorted[k + i];
#pragma unroll
        for (int i = 0; i < 8; ++i) ee[i] = a_s[s[i] * NH + head];
#pragma unroll
        for (int i = 0; i < 8; ++i) v[i] = h_bf[s[i] * 64 + lane];
#pragma unroll
        for (int i = 0; i < 8; ++i) {
            float e0 = ee[i] + ad;
            e0 = (e0 >= 0.f) ? e0 : NEG_SLOPE * e0;
            float w0 = __expf(e0);
            denom += w0;
            ax += w0 * __uint_as_float(v[i] << 16);
            ay += w0 * __uint_as_float(v[i] & 0xffff0000u);
        }
    }
    for (; k < hi; ++k) {
        int s0 = src_sorted[k];
        float e0 = a_s[s0 * NH + head] + ad;
        unsigned v0 = h_bf[s0 * 64 + lane];
        e0 = (e0 >= 0.f) ? e0 : NEG_SLOPE * e0;
        float w0 = __expf(e0);
        denom += w0;
        ax += w0 * __uint_as_float(v0 << 16);
        ay += w0 * __uint_as_float(v0 & 0xffff0000u);
    }

    float inv = 1.f / denom;
    float ox = ax * inv + bi0;
    float oy = ay * inv + bi1;
    ox = (ox > 0.f) ? ox : expm1f(ox);
    oy = (oy > 0.f) ? oy : expm1f(oy);
    ox += __uint_as_float(rv << 16) + rb0;
    oy += __uint_as_float(rv & 0xffff0000u) + rb1;
    float mean = wave_bcast_sum(ox + oy) * (1.f / HC);
    float dx = ox - mean, dy = oy - mean;
    float var = wave_bcast_sum(dx * dx + dy * dy) * (1.f / HC);
    float rs = rsqrtf(var + LN_EPS);
    *(float2*)&out[d * HC + c0] =
        make_float2(g0 * dx * rs + lb0, g1 * dy * rs + lb1);
}

// ---------------------------------------------------------------------------
extern "C" void kernel_launch(void* const* d_in, const int* in_sizes, int n_in,
                              void* d_out, int out_size, void* d_ws, size_t ws_size,
                              hipStream_t stream) {
    const float* x       = (const float*)d_in[0];
    const int*   ei      = (const int*)d_in[1];
    const float* W       = (const float*)d_in[2];
    const float* att_src = (const float*)d_in[3];
    const float* att_dst = (const float*)d_in[4];
    const float* bias    = (const float*)d_in[5];
    const float* res_w   = (const float*)d_in[6];
    const float* res_b   = (const float*)d_in[7];
    const float* ln_g    = (const float*)d_in[8];
    const float* ln_b    = (const float*)d_in[9];
    float* out = (float*)d_out;

    int n = in_sizes[0] / F_IN;              // 50000 (<= 65536 for packing)
    int E = in_sizes[1] / 2;                 // 800000
    int NB = (n + BUCKET - 1) / BUCKET;      // 391 buckets (<= 512)
    int chunk = (E + NC_CHUNK - 1) / NC_CHUNK;
    int nka = (n + 63) / 64;                 // 782 kA blocks

    unsigned* h_bf     = (unsigned*)d_ws;                  // n*64 dwords
    unsigned* r_bf     = h_bf + (size_t)n * 64;            // n*64 dwords
    float*    a_s      = (float*)(r_bf + (size_t)n * 64);  // n*NH
    float*    a_d      = a_s + (size_t)n * NH;             // n*NH
    int*      counts   = (int*)(a_d + (size_t)n * NH);     // NC_CHUNK*NB
    int*      sbase_g  = counts + NC_CHUNK * NB;           // NB+1
    int*      epacked  = sbase_g + (NB + 2);               // E
    int*      ssorted  = epacked + E;                      // E
    int*      offsets  = ssorted + E;                      // n+1
    __bf16*   wt       = (__bf16*)(offsets + (n + 2));     // 256*64 bf16 = 32 KB

    k_prep<<<KW_BLOCKS + NC_CHUNK, 256, 0, stream>>>(
        W, res_w, ei, E, wt, counts, NB, chunk);

    k_main<<<nka + NC_CHUNK, 256, 0, stream>>>(
        x, wt, att_src, att_dst, h_bf, r_bf, a_s, a_d, n, nka,
        ei, E, counts, epacked, sbase_g, NB, chunk);

    kd_sort<<<NB, 256, 0, stream>>>(sbase_g, epacked, ssorted, offsets, NB, n, E);

    k_agg<<<(n + 3) / 4, 256, 0, stream>>>(offsets, ssorted, a_s, a_d, h_bf, r_bf,
                                           bias, res_b, ln_g, ln_b, out, n);
}

// Round 13
// 189.269 us; speedup vs baseline: 1.2346x; 1.0185x over previous
//
#include <hip/hip_runtime.h>

#define F_IN 64
#define NH 4
#define HC 128
#define NEG_SLOPE 0.2f
#define LN_EPS 1e-5f
#define NC_CHUNK 128          // number of edge chunks
#define BUCKET 128            // dst nodes per bucket
#define KW_BLOCKS 64          // blocks doing the W transpose in k_prep

typedef __bf16 bf16_8 __attribute__((ext_vector_type(8)));
typedef float  f32_4  __attribute__((ext_vector_type(4)));

// ---------------------------------------------------------------------------
// Inline per-wave int64-vs-int32 detection (all-zero odd dwords <=> int64).
// ---------------------------------------------------------------------------
__device__ inline int detect_is64(const int* __restrict__ ei, int E) {
    int lane = threadIdx.x & 63;
    long long stride = (2LL * E) / 65;
    int w = ei[(((long long)(lane + 1)) * stride) | 1];
    return __ballot(w != 0) == 0ULL;
}

__device__ inline unsigned bfpack(float a, float b) {
    unsigned ua = __float_as_uint(a), ub = __float_as_uint(b);
    ua = (ua + 0x7fffu + ((ua >> 16) & 1u)) >> 16;           // RNE to bf16
    ub = (ub + 0x7fffu + ((ub >> 16) & 1u)) >> 16;
    return ua | (ub << 16);
}

// ---------------------------------------------------------------------------
// K_prep: blocks [0,64) transpose Wcat -> bf16 wt; blocks [64,192) per-chunk
// dst-bucket histogram -> counts[c*NB+b].
// ---------------------------------------------------------------------------
__global__ __launch_bounds__(256) void k_prep(
    const float* __restrict__ W, const float* __restrict__ res_w,
    const int* __restrict__ ei, int E,
    __bf16* __restrict__ wt, int* __restrict__ counts, int NB, int chunk)
{
    if ((int)blockIdx.x < KW_BLOCKS) {
        int idx = blockIdx.x * 256 + threadIdx.x;    // 0..16383
        int ch = idx >> 6, k = idx & 63;
        const float* src = (ch < HC) ? W : res_w;
        wt[ch * 64 + k] = (__bf16)src[k * HC + (ch & (HC - 1))];
        return;
    }
    __shared__ int cnt[512];
    int c = blockIdx.x - KW_BLOCKS;
    for (int i = threadIdx.x; i < NB; i += 256) cnt[i] = 0;
    __syncthreads();
    int is64 = detect_is64(ei, E);
    int base = c * chunk, end = min(E, base + chunk);
    for (int idx = base + threadIdx.x; idx < end; idx += 256) {
        int d = is64 ? ei[2 * (E + idx)] : ei[E + idx];
        atomicAdd(&cnt[d >> 7], 1);
    }
    __syncthreads();
    for (int b = threadIdx.x; b < NB; b += 256)
        counts[c * NB + b] = cnt[b];
}

// ---------------------------------------------------------------------------
// K_main: blocks [0,nka): kA MFMA dual-GEMM, 2 node-sets per wave (A reuse);
//         blocks [nka, nka+128): kc_scatter with in-block offset computation.
// ---------------------------------------------------------------------------
__global__ __launch_bounds__(256) void k_main(
    const float* __restrict__ x, const __bf16* __restrict__ wt,
    const float* __restrict__ att_src, const float* __restrict__ att_dst,
    unsigned* __restrict__ h_bf, unsigned* __restrict__ r_bf,
    float* __restrict__ a_s, float* __restrict__ a_d, int n, int nka,
    const int* __restrict__ ei, int E, const int* __restrict__ counts,
    int* __restrict__ epacked, int* __restrict__ sbase_g, int NB, int chunk)
{
    __shared__ int cur[512];
    __shared__ int ss[256];

    if ((int)blockIdx.x < nka) {
        // ---------------- kA path: 128 nodes/block, 2 sets per wave --------
        int tid = threadIdx.x;
        int wv_ = tid >> 6, lane = tid & 63;
        int col = lane & 15, quad = lane >> 4;
        int base = blockIdx.x * 128;
        int node0 = base + wv_ * 16 + col;
        int node1 = node0 + 64;
        int nr0 = (node0 < n) ? node0 : (n - 1);
        int nr1 = (node1 < n) ? node1 : (n - 1);

        bf16_8 b0x0, b0x1, b1x0, b1x1;
        {
            const float* xp = &x[nr0 * F_IN + quad * 8];
            float4 p0 = *(const float4*)(xp);
            float4 p1 = *(const float4*)(xp + 4);
            float4 p2 = *(const float4*)(xp + 32);
            float4 p3 = *(const float4*)(xp + 36);
            b0x0[0] = (__bf16)p0.x; b0x0[1] = (__bf16)p0.y; b0x0[2] = (__bf16)p0.z; b0x0[3] = (__bf16)p0.w;
            b0x0[4] = (__bf16)p1.x; b0x0[5] = (__bf16)p1.y; b0x0[6] = (__bf16)p1.z; b0x0[7] = (__bf16)p1.w;
            b0x1[0] = (__bf16)p2.x; b0x1[1] = (__bf16)p2.y; b0x1[2] = (__bf16)p2.z; b0x1[3] = (__bf16)p2.w;
            b0x1[4] = (__bf16)p3.x; b0x1[5] = (__bf16)p3.y; b0x1[6] = (__bf16)p3.z; b0x1[7] = (__bf16)p3.w;
        }
        {
            const float* xp = &x[nr1 * F_IN + quad * 8];
            float4 p0 = *(const float4*)(xp);
            float4 p1 = *(const float4*)(xp + 4);
            float4 p2 = *(const float4*)(xp + 32);
            float4 p3 = *(const float4*)(xp + 36);
            b1x0[0] = (__bf16)p0.x; b1x0[1] = (__bf16)p0.y; b1x0[2] = (__bf16)p0.z; b1x0[3] = (__bf16)p0.w;
            b1x0[4] = (__bf16)p1.x; b1x0[5] = (__bf16)p1.y; b1x0[6] = (__bf16)p1.z; b1x0[7] = (__bf16)p1.w;
            b1x1[0] = (__bf16)p2.x; b1x1[1] = (__bf16)p2.y; b1x1[2] = (__bf16)p2.z; b1x1[3] = (__bf16)p2.w;
            b1x1[4] = (__bf16)p3.x; b1x1[5] = (__bf16)p3.y; b1x1[6] = (__bf16)p3.z; b1x1[7] = (__bf16)p3.w;
        }

        float vs0[4] = {0,0,0,0}, vd0[4] = {0,0,0,0};
        float vs1[4] = {0,0,0,0}, vd1[4] = {0,0,0,0};

#pragma unroll
        for (int mt = 0; mt < 16; ++mt) {
            const __bf16* ap = &wt[(mt * 16 + col) * 64 + quad * 8];
            bf16_8 a0 = *(const bf16_8*)ap;
            bf16_8 a1 = *(const bf16_8*)(ap + 32);
            f32_4 acc0 = {0.f, 0.f, 0.f, 0.f};
            acc0 = __builtin_amdgcn_mfma_f32_16x16x32_bf16(a0, b0x0, acc0, 0, 0, 0);
            acc0 = __builtin_amdgcn_mfma_f32_16x16x32_bf16(a1, b0x1, acc0, 0, 0, 0);
            f32_4 acc1 = {0.f, 0.f, 0.f, 0.f};
            acc1 = __builtin_amdgcn_mfma_f32_16x16x32_bf16(a0, b1x0, acc1, 0, 0, 0);
            acc1 = __builtin_amdgcn_mfma_f32_16x16x32_bf16(a1, b1x1, acc1, 0, 0, 0);
            int ch0 = mt * 16 + quad * 4;
            if (mt < 8) {
                float4 as4 = *(const float4*)&att_src[ch0];
                float4 ad4 = *(const float4*)&att_dst[ch0];
                int head = mt >> 1;
                vs0[head] += acc0[0]*as4.x + acc0[1]*as4.y + acc0[2]*as4.z + acc0[3]*as4.w;
                vd0[head] += acc0[0]*ad4.x + acc0[1]*ad4.y + acc0[2]*ad4.z + acc0[3]*ad4.w;
                vs1[head] += acc1[0]*as4.x + acc1[1]*as4.y + acc1[2]*as4.z + acc1[3]*as4.w;
                vd1[head] += acc1[0]*ad4.x + acc1[1]*ad4.y + acc1[2]*ad4.z + acc1[3]*ad4.w;
                if (node0 < n) {
                    uint2 pk = make_uint2(bfpack(acc0[0], acc0[1]), bfpack(acc0[2], acc0[3]));
                    *(uint2*)&h_bf[node0 * 64 + (ch0 >> 1)] = pk;
                }
                if (node1 < n) {
                    uint2 pk = make_uint2(bfpack(acc1[0], acc1[1]), bfpack(acc1[2], acc1[3]));
                    *(uint2*)&h_bf[node1 * 64 + (ch0 >> 1)] = pk;
                }
            } else {
                if (node0 < n) {
                    uint2 pk = make_uint2(bfpack(acc0[0], acc0[1]), bfpack(acc0[2], acc0[3]));
                    *(uint2*)&r_bf[node0 * 64 + ((ch0 - 128) >> 1)] = pk;
                }
                if (node1 < n) {
                    uint2 pk = make_uint2(bfpack(acc1[0], acc1[1]), bfpack(acc1[2], acc1[3]));
                    *(uint2*)&r_bf[node1 * 64 + ((ch0 - 128) >> 1)] = pk;
                }
            }
        }

#pragma unroll
        for (int hh = 0; hh < NH; ++hh) {
            vs0[hh] += __shfl_down(vs0[hh], 32, 64); vs0[hh] += __shfl_down(vs0[hh], 16, 64);
            vd0[hh] += __shfl_down(vd0[hh], 32, 64); vd0[hh] += __shfl_down(vd0[hh], 16, 64);
            vs1[hh] += __shfl_down(vs1[hh], 32, 64); vs1[hh] += __shfl_down(vs1[hh], 16, 64);
            vd1[hh] += __shfl_down(vd1[hh], 32, 64); vd1[hh] += __shfl_down(vd1[hh], 16, 64);
        }
        if (quad == 0) {
            if (node0 < n) {
                *(float4*)&a_s[node0 * NH] = make_float4(vs0[0], vs0[1], vs0[2], vs0[3]);
                *(float4*)&a_d[node0 * NH] = make_float4(vd0[0], vd0[1], vd0[2], vd0[3]);
            }
            if (node1 < n) {
                *(float4*)&a_s[node1 * NH] = make_float4(vs1[0], vs1[1], vs1[2], vs1[3]);
                *(float4*)&a_d[node1 * NH] = make_float4(vd1[0], vd1[1], vd1[2], vd1[3]);
            }
        }
        return;
    }

    // ---------------- scatter path ----------------
    int c = blockIdx.x - nka;
    int t = threadIdx.x;
    int b0 = 2 * t, b1 = 2 * t + 1;

    int f0 = 0, f1 = 0, p0 = 0, p1 = 0;
    for (int cc = 0; cc < NC_CHUNK; ++cc) {
        int v0 = (b0 < NB) ? counts[cc * NB + b0] : 0;
        int v1 = (b1 < NB) ? counts[cc * NB + b1] : 0;
        f0 += v0; f1 += v1;
        if (cc < c) { p0 += v0; p1 += v1; }
    }
    ss[t] = f0 + f1;
    __syncthreads();
#pragma unroll
    for (int off = 1; off < 256; off <<= 1) {
        int u = (t >= off) ? ss[t - off] : 0;
        __syncthreads();
        ss[t] += u;
        __syncthreads();
    }
    int ebase = ss[t] - (f0 + f1);
    int base0 = ebase, base1 = ebase + f0;
    if (b0 < NB) cur[b0] = base0 + p0;
    if (b1 < NB) cur[b1] = base1 + p1;
    if (c == 0) {
        if (b0 <= NB) sbase_g[b0] = base0;
        if (b1 <= NB) sbase_g[b1] = base1;
    }
    __syncthreads();

    int is64 = detect_is64(ei, E);
    int base = c * chunk, end = min(E, base + chunk);
    for (int idx = base + t; idx < end; idx += 256) {
        int s = is64 ? ei[2 * idx] : ei[idx];
        int d = is64 ? ei[2 * (E + idx)] : ei[E + idx];
        int p = atomicAdd(&cur[d >> 7], 1);
        epacked[p] = ((d & (BUCKET - 1)) << 16) | s;
    }
}

// ---------------------------------------------------------------------------
// KD_sort: one block per bucket -> per-dst CSR order; emits node offsets.
// ---------------------------------------------------------------------------
__global__ __launch_bounds__(256) void kd_sort(
    const int* __restrict__ sbase_g, const int* __restrict__ epacked,
    int* __restrict__ sorted_src, int* __restrict__ offsets,
    int NB, int n, int E)
{
    __shared__ int hist[BUCKET];
    __shared__ int sc[BUCKET];
    __shared__ int cur[BUCKET];
    int b = blockIdx.x;
    int s0 = sbase_g[b];
    int s1 = sbase_g[b + 1];
    int t = threadIdx.x;
    if (t < BUCKET) hist[t] = 0;
    __syncthreads();
    for (int e = s0 + t; e < s1; e += 256)
        atomicAdd(&hist[((unsigned)epacked[e]) >> 16], 1);
    __syncthreads();
    if (t < BUCKET) sc[t] = hist[t];
    __syncthreads();
#pragma unroll
    for (int o = 1; o < BUCKET; o <<= 1) {
        int u = (t >= o && t < BUCKET) ? sc[t - o] : 0;
        __syncthreads();
        if (t < BUCKET) sc[t] += u;
        __syncthreads();
    }
    if (t < BUCKET) {
        int excl = sc[t] - hist[t];
        cur[t] = s0 + excl;
        int d = b * BUCKET + t;
        if (d < n) offsets[d] = s0 + excl;
    }
    if (b == NB - 1 && t == 0) offsets[n] = E;
    __syncthreads();
    for (int e = s0 + t; e < s1; e += 256) {
        int p = epacked[e];
        int pos = atomicAdd(&cur[((unsigned)p) >> 16], 1);
        sorted_src[pos] = p & 0xFFFF;
    }
}

// ---------------------------------------------------------------------------
// K_agg: wave-per-dst, 2 EDGES per iteration (eh = lane>>5 selects edge,
// g = lane&31 -> 4 channels). Cross-half merge via shfl_xor(32). Register
// accumulation, no atomics, fused epilogue.
// ---------------------------------------------------------------------------
__global__ __launch_bounds__(256) void k_agg(
    const int* __restrict__ offsets, const int* __restrict__ src_sorted,
    const float* __restrict__ a_s, const float* __restrict__ a_d,
    const unsigned int* __restrict__ h_bf, const unsigned int* __restrict__ r_bf,
    const float* __restrict__ bias, const float* __restrict__ res_b,
    const float* __restrict__ ln_g, const float* __restrict__ ln_b,
    float* __restrict__ out, int n)
{
    int wv = threadIdx.x >> 6, lane = threadIdx.x & 63;
    int d = blockIdx.x * 4 + wv;
    if (d >= n) return;
    int eh = lane >> 5, g = lane & 31;       // edge-half, channel group (4 ch)
    int head = g >> 3;
    float ad = a_d[d * NH + head];

    float a0 = 0.f, a1 = 0.f, a2 = 0.f, a3 = 0.f, denom = 0.f;

    // self-loop on eh=0 half only
    {
        float e = a_s[d * NH + head] + ad;
        e = (e >= 0.f) ? e : NEG_SLOPE * e;
        float w = (eh == 0) ? __expf(e) : 0.f;
        uint2 hv = *(const uint2*)&h_bf[d * 64 + 2 * g];
        a0 += w * __uint_as_float(hv.x << 16);
        a1 += w * __uint_as_float(hv.x & 0xffff0000u);
        a2 += w * __uint_as_float(hv.y << 16);
        a3 += w * __uint_as_float(hv.y & 0xffff0000u);
        denom += w;
    }

    int lo = offsets[d], hi = offsets[d + 1];
    int k = lo;
    // main loop: 4 pairs = 8 edges, all in-range
    for (; k + 7 < hi; k += 8) {
        int s[4]; float ee[4]; uint2 v[4];
#pragma unroll
        for (int i = 0; i < 4; ++i) s[i] = src_sorted[k + 2 * i + eh];
#pragma unroll
        for (int i = 0; i < 4; ++i) ee[i] = a_s[s[i] * NH + head];
#pragma unroll
        for (int i = 0; i < 4; ++i) v[i] = *(const uint2*)&h_bf[s[i] * 64 + 2 * g];
#pragma unroll
        for (int i = 0; i < 4; ++i) {
            float e0 = ee[i] + ad;
            e0 = (e0 >= 0.f) ? e0 : NEG_SLOPE * e0;
            float w0 = __expf(e0);
            denom += w0;
            a0 += w0 * __uint_as_float(v[i].x << 16);
            a1 += w0 * __uint_as_float(v[i].x & 0xffff0000u);
            a2 += w0 * __uint_as_float(v[i].y << 16);
            a3 += w0 * __uint_as_float(v[i].y & 0xffff0000u);
        }
    }
    // tail: pairs with per-lane guard
    for (; k < hi; k += 2) {
        int idx = k + eh;
        int valid = idx < hi;
        int s0 = valid ? src_sorted[idx] : 0;
        float e0 = a_s[s0 * NH + head] + ad;
        uint2 v0 = *(const uint2*)&h_bf[s0 * 64 + 2 * g];
        e0 = (e0 >= 0.f) ? e0 : NEG_SLOPE * e0;
        float w0 = valid ? __expf(e0) : 0.f;
        denom += w0;
        a0 += w0 * __uint_as_float(v0.x << 16);
        a1 += w0 * __uint_as_float(v0.x & 0xffff0000u);
        a2 += w0 * __uint_as_float(v0.y << 16);
        a3 += w0 * __uint_as_float(v0.y & 0xffff0000u);
    }

    // cross-half merge: partner lane (g same, other eh) holds the other
    // edges' partials for the SAME channels
    a0 += __shfl_xor(a0, 32, 64);
    a1 += __shfl_xor(a1, 32, 64);
    a2 += __shfl_xor(a2, 32, 64);
    a3 += __shfl_xor(a3, 32, 64);
    denom += __shfl_xor(denom, 32, 64);

    int c0 = g * 4;
    float4 bi = *(const float4*)&bias[c0];
    float4 rb = *(const float4*)&res_b[c0];
    float4 gg = *(const float4*)&ln_g[c0];
    float4 lb = *(const float4*)&ln_b[c0];
    uint2 rv = *(const uint2*)&r_bf[d * 64 + 2 * g];

    float inv = 1.f / denom;
    float o0 = a0 * inv + bi.x;
    float o1 = a1 * inv + bi.y;
    float o2 = a2 * inv + bi.z;
    float o3 = a3 * inv + bi.w;
    o0 = (o0 > 0.f) ? o0 : expm1f(o0);
    o1 = (o1 > 0.f) ? o1 : expm1f(o1);
    o2 = (o2 > 0.f) ? o2 : expm1f(o2);
    o3 = (o3 > 0.f) ? o3 : expm1f(o3);
    o0 += __uint_as_float(rv.x << 16) + rb.x;
    o1 += __uint_as_float(rv.x & 0xffff0000u) + rb.y;
    o2 += __uint_as_float(rv.y << 16) + rb.z;
    o3 += __uint_as_float(rv.y & 0xffff0000u) + rb.w;

    // LN: both halves hold identical values -> full-wave sum = 2x total
    float ps = o0 + o1 + o2 + o3;
#pragma unroll
    for (int off = 32; off > 0; off >>= 1) ps += __shfl_down(ps, off, 64);
    float mean = __shfl(ps, 0, 64) * (1.f / (2 * HC));
    float d0 = o0 - mean, d1 = o1 - mean, d2 = o2 - mean, d3 = o3 - mean;
    float pv = d0 * d0 + d1 * d1 + d2 * d2 + d3 * d3;
#pragma unroll
    for (int off = 32; off > 0; off >>= 1) pv += __shfl_down(pv, off, 64);
    float var = __shfl(pv, 0, 64) * (1.f / (2 * HC));
    float rs = rsqrtf(var + LN_EPS);
    if (eh == 0) {
        *(float4*)&out[d * HC + c0] =
            make_float4(gg.x * d0 * rs + lb.x, gg.y * d1 * rs + lb.y,
                        gg.z * d2 * rs + lb.z, gg.w * d3 * rs + lb.w);
    }
}

// ---------------------------------------------------------------------------
extern "C" void kernel_launch(void* const* d_in, const int* in_sizes, int n_in,
                              void* d_out, int out_size, void* d_ws, size_t ws_size,
                              hipStream_t stream) {
    const float* x       = (const float*)d_in[0];
    const int*   ei      = (const int*)d_in[1];
    const float* W       = (const float*)d_in[2];
    const float* att_src = (const float*)d_in[3];
    const float* att_dst = (const float*)d_in[4];
    const float* bias    = (const float*)d_in[5];
    const float* res_w   = (const float*)d_in[6];
    const float* res_b   = (const float*)d_in[7];
    const float* ln_g    = (const float*)d_in[8];
    const float* ln_b    = (const float*)d_in[9];
    float* out = (float*)d_out;

    int n = in_sizes[0] / F_IN;              // 50000 (<= 65536 for packing)
    int E = in_sizes[1] / 2;                 // 800000
    int NB = (n + BUCKET - 1) / BUCKET;      // 391 buckets (<= 512)
    int chunk = (E + NC_CHUNK - 1) / NC_CHUNK;
    int nka = (n + 127) / 128;               // 391 kA blocks (2 sets/wave)

    unsigned* h_bf     = (unsigned*)d_ws;                  // n*64 dwords
    unsigned* r_bf     = h_bf + (size_t)n * 64;            // n*64 dwords
    float*    a_s      = (float*)(r_bf + (size_t)n * 64);  // n*NH
    float*    a_d      = a_s + (size_t)n * NH;             // n*NH
    int*      counts   = (int*)(a_d + (size_t)n * NH);     // NC_CHUNK*NB
    int*      sbase_g  = counts + NC_CHUNK * NB;           // NB+1
    int*      epacked  = sbase_g + (NB + 2);               // E
    int*      ssorted  = epacked + E;                      // E
    int*      offsets  = ssorted + E;                      // n+1
    __bf16*   wt       = (__bf16*)(offsets + (n + 2));     // 256*64 bf16 = 32 KB

    k_prep<<<KW_BLOCKS + NC_CHUNK, 256, 0, stream>>>(
        W, res_w, ei, E, wt, counts, NB, chunk);

    k_main<<<nka + NC_CHUNK, 256, 0, stream>>>(
        x, wt, att_src, att_dst, h_bf, r_bf, a_s, a_d, n, nka,
        ei, E, counts, epacked, sbase_g, NB, chunk);

    kd_sort<<<NB, 256, 0, stream>>>(sbase_g, epacked, ssorted, offsets, NB, n, E);

    k_agg<<<(n + 3) / 4, 256, 0, stream>>>(offsets, ssorted, a_s, a_d, h_bf, r_bf,
                                           bias, res_b, ln_g, ln_b, out, n);
}